// Round 10
// baseline (439.196 us; speedup 1.0000x reference)
//
#include <hip/hip_runtime.h>

typedef __attribute__((ext_vector_type(8))) short s16x8;
typedef __attribute__((ext_vector_type(4))) float f32x4;

#define MFMA16 __builtin_amdgcn_mfma_f32_16x16x32_bf16
#define SBAR() asm volatile("s_barrier" ::: "memory")
#define WAITLGKM0() asm volatile("s_waitcnt lgkmcnt(0)" ::: "memory")

__device__ __forceinline__ short f2bf(float x) {
  union { float f; unsigned u; } c; c.f = x;
  unsigned r = (c.u + 0x7fffu + ((c.u >> 16) & 1u)) >> 16;
  return (short)r;
}

__device__ __forceinline__ void gld16(const void* g, void* l) {
  __builtin_amdgcn_global_load_lds(
      (const __attribute__((address_space(1))) unsigned*)g,
      (__attribute__((address_space(3))) unsigned*)l, 16, 0, 0);
}

// Fragment loads are global->register: for a row-major [R][K] bf16 matrix the
// MFMA16 frag at (row16, kslice) has lane quads (l, l+16, l+32, l+48) reading
// one contiguous 64-B line -> 16 dense lines per b128 load. No LDS staging.
// Only Ws (phase-1 B, swizzled BK=32 tiles) and P (phase-2 B) live in LDS.

// ---------------------------------------------------------------------------
// Prep
// ---------------------------------------------------------------------------
__global__ __launch_bounds__(256) void k_cvt_l1(const float* __restrict__ L1,
                                                short* __restrict__ L1b) {
  int i = blockIdx.x * 256 + threadIdx.x;
  L1b[i] = f2bf(L1[i]);
}

__global__ __launch_bounds__(256) void k_build_l2cat(const float* __restrict__ L2,
                                                     short* __restrict__ L2cat) {
  __shared__ float t[32][33];
  const int l = blockIdx.z, w0 = blockIdx.x * 32, z0 = blockIdx.y * 32;
  const int tx = threadIdx.x, ty = threadIdx.y;
  const float* src = L2 + (size_t)l * 65536;
  for (int i = ty; i < 32; i += 8) t[i][tx] = src[(size_t)(w0 + i) * 256 + z0 + tx];
  __syncthreads();
  for (int i = ty; i < 32; i += 8)
    L2cat[(size_t)(z0 + i) * 768 + l * 256 + w0 + tx] = f2bf(t[tx][i]);
}

__global__ __launch_bounds__(256) void k_build_wt(const float* __restrict__ W,
                                                  short* __restrict__ WT) {
  for (int idx = threadIdx.x + blockIdx.x * 256; idx < 192 * 192; idx += 256 * gridDim.x) {
    int lo = idx / 192, kf = idx % 192;
    int l = lo >> 6, o = lo & 63, k = kf / 64, f = kf & 63;
    WT[idx] = f2bf(W[(((size_t)(k * 3 + l) * 64 + f) << 6) + o]);
  }
}

__global__ __launch_bounds__(256) void k_cvt_ht(const float* __restrict__ H,
                                                short* __restrict__ HbT, int b0) {
  __shared__ float t[32][33];
  const int bc = blockIdx.z;
  const int wf0 = blockIdx.x * 32, v0 = blockIdx.y * 32;
  const int tx = threadIdx.x, ty = threadIdx.y;
  const float* src = H + ((size_t)(b0 + bc) * 256 + v0) * 16384;
  for (int i = ty; i < 32; i += 8) t[i][tx] = src[(size_t)i * 16384 + wf0 + tx];
  __syncthreads();
  short* dst = HbT + ((size_t)bc * 16384 + wf0) * 256;
  for (int i = ty; i < 32; i += 8) dst[(size_t)i * 256 + v0 + tx] = f2bf(t[tx][i]);
}

// ---------------------------------------------------------------------------
// S1: A2[((bc*256+u)*256+w)*192 + kk*64+f] = sum_v L1b[kk][u][v]*HbT[bc][w*64+f][v]
// 128x128 tile, ZERO LDS, zero barriers: both frags global->reg, full unroll.
// ---------------------------------------------------------------------------
__global__ __launch_bounds__(256, 3) void k_s1(const short* __restrict__ L1b,
                                               const short* __restrict__ HbT,
                                               short* __restrict__ A2) {
  const int t = threadIdx.x, lane = t & 63, wid = t >> 6;
  const int n0 = blockIdx.x * 128;
  const int kk = blockIdx.y >> 1;
  const int u0 = (blockIdx.y & 1) * 128;
  const int bc = blockIdx.z;
  const short* Ag = L1b + (size_t)kk * 65536;        // [u][v]
  const short* Bg = HbT + (size_t)bc * 16384 * 256;  // [n][v]
  const int wm = wid >> 1, wn = wid & 1;
  const int ar = lane & 15, ks8 = (lane >> 4) * 8;
  f32x4 acc[4][4] = {};
#pragma unroll
  for (int kt = 0; kt < 8; ++kt) {
    s16x8 a[4], b[4];
#pragma unroll
    for (int i = 0; i < 4; ++i)
      a[i] = *(const s16x8*)&Ag[(size_t)(u0 + wm * 64 + i * 16 + ar) * 256 + kt * 32 + ks8];
#pragma unroll
    for (int j = 0; j < 4; ++j)
      b[j] = *(const s16x8*)&Bg[(size_t)(n0 + wn * 64 + j * 16 + ar) * 256 + kt * 32 + ks8];
#pragma unroll
    for (int i = 0; i < 4; ++i)
#pragma unroll
      for (int j = 0; j < 4; ++j) acc[i][j] = MFMA16(a[i], b[j], acc[i][j], 0, 0, 0);
  }
  const int cr = lane >> 4, cc = lane & 15;
#pragma unroll
  for (int i = 0; i < 4; ++i)
#pragma unroll
    for (int j = 0; j < 4; ++j) {
      const int ncol = n0 + wn * 64 + j * 16 + cc;
      const int w = ncol >> 6, f = ncol & 63;
#pragma unroll
      for (int r = 0; r < 4; ++r) {
        const int u = u0 + wm * 64 + i * 16 + cr * 4 + r;
        A2[(((size_t)bc * 256 + u) * 256 + w) * 192 + kk * 64 + f] = f2bf(acc[i][j][r]);
      }
    }
}

// ---------------------------------------------------------------------------
// S2+S3 fused, one block per bu (512 thr). LDS = 96 KB: P[64][768]
// (Ws 72 KB overlaid). A-operands of BOTH phases are global->reg (A2 rows /
// L2cat rows: L2-resident). Loops barrier-free, fully unrolled; compiler
// pipelines loads. Only syncs: prologue syncthreads + the 2 P-handoff points.
// ---------------------------------------------------------------------------
__global__ __launch_bounds__(512, 2) void k_s23(const short* __restrict__ A2,
                                                const short* __restrict__ WTg,
                                                const short* __restrict__ L2cat,
                                                const float* __restrict__ bias,
                                                float* __restrict__ out, int b0) {
  __shared__ __align__(16) short P[64 * 768];  // 96 KB; Ws overlays [0,72K)
  short* Ws = P;
  const int t = threadIdx.x, lane = t & 63, wid = t >> 6;
  const int bul = blockIdx.x;
  const int ar = lane & 15, cc = ar, cr = lane >> 4, sl = lane & 7, ks = lane >> 4;
  const int ks8 = ks * 8;
  const int srow = lane >> 2;
  const int selem = ((lane & 3) ^ ((lane >> 3) & 3)) * 8;
  const int koff = ((lane >> 4) ^ ((lane >> 1) & 3)) * 8;
  const short* A2g = A2 + (size_t)bul * 49152;

  // prologue: stage Ws (192 lo x 192 kf, swizzled BK=32 tiles)
  for (int s = wid; s < 72; s += 8) {
    const int t6 = s / 12, g = (s % 12) * 16;
    gld16(WTg + (size_t)(g + srow) * 192 + t6 * 32 + selem, Ws + ((size_t)t6 * 192 + g) * 32);
  }
  __syncthreads();  // Ws resident

  // ---- Phase 1: (192 lo) x (own 32 w), K=192, 6 iters, a from global ----
  f32x4 acc[12][2] = {};
#pragma unroll
  for (int kt6 = 0; kt6 < 6; ++kt6) {
    s16x8 a0 = *(const s16x8*)&A2g[(size_t)(wid * 32 + ar) * 192 + kt6 * 32 + ks8];
    s16x8 a1 = *(const s16x8*)&A2g[(size_t)(wid * 32 + 16 + ar) * 192 + kt6 * 32 + ks8];
#pragma unroll
    for (int j2 = 0; j2 < 12; ++j2) {
      s16x8 b = *(const s16x8*)&Ws[((size_t)kt6 * 192 + j2 * 16 + ar) * 32 + koff];
      acc[j2][0] = MFMA16(a0, b, acc[j2][0], 0, 0, 0);
      acc[j2][1] = MFMA16(a1, b, acc[j2][1], 0, 0, 0);
    }
  }
  WAITLGKM0();  // this wave's Ws reads complete
  SBAR();       // all waves done reading Ws; region becomes P

  // acc -> P (packed b32, swizzled slots)
#pragma unroll
  for (int j2 = 0; j2 < 12; ++j2)
#pragma unroll
    for (int i = 0; i < 2; ++i)
#pragma unroll
      for (int rp = 0; rp < 2; ++rp) {
        const int r = rp * 2;
        const int w = wid * 32 + i * 16 + cr * 4 + r;
        const int lo = j2 * 16 + cc;
        const int l = lo >> 6, o = lo & 63;
        const int lw = l * 256 + w;
        const int addr = o * 768 + ((lw >> 3) ^ (o & 7)) * 8 + (lw & 7);
        unsigned lo16 = (unsigned short)f2bf(acc[j2][i][r]);
        unsigned hi16 = (unsigned short)f2bf(acc[j2][i][r + 1]);
        *(unsigned*)&P[addr] = lo16 | (hi16 << 16);
      }
  WAITLGKM0();  // P ds_writes drained
  SBAR();       // P visible to all waves

  // ---- Phase 2: (own 32 z) x (64 o), K=768, 24 iters, a from global ----
  f32x4 acc2[2][4] = {};
#pragma unroll
  for (int t2 = 0; t2 < 24; ++t2) {
    s16x8 a0 = *(const s16x8*)&L2cat[(size_t)(wid * 32 + ar) * 768 + t2 * 32 + ks8];
    s16x8 a1 = *(const s16x8*)&L2cat[(size_t)(wid * 32 + 16 + ar) * 768 + t2 * 32 + ks8];
    const int S = t2 * 4 + ks;
#pragma unroll
    for (int j = 0; j < 4; ++j) {
      s16x8 b = *(const s16x8*)&P[(j * 16 + ar) * 768 + (S ^ sl) * 8];
      acc2[0][j] = MFMA16(a0, b, acc2[0][j], 0, 0, 0);
      acc2[1][j] = MFMA16(a1, b, acc2[1][j], 0, 0, 0);
    }
  }

  // epilogue
  float* og = out + ((size_t)b0 * 256 + bul) * 16384;
#pragma unroll
  for (int i = 0; i < 2; ++i)
#pragma unroll
    for (int j = 0; j < 4; ++j) {
      const float bv = bias[j * 16 + cc];
#pragma unroll
      for (int r = 0; r < 4; ++r) {
        const int z = wid * 32 + i * 16 + cr * 4 + r;
        og[(size_t)z * 64 + j * 16 + cc] = fmaxf(acc2[i][j][r] + bv, 0.f);
      }
    }
}

// ---------------------------------------------------------------------------
extern "C" void kernel_launch(void* const* d_in, const int* in_sizes, int n_in,
                              void* d_out, int out_size, void* d_ws, size_t ws_size,
                              hipStream_t stream) {
  const float* H    = (const float*)d_in[0];
  const float* L1   = (const float*)d_in[1];
  const float* L2   = (const float*)d_in[2];
  const float* W    = (const float*)d_in[3];
  const float* bias = (const float*)d_in[4];
  float* out = (float*)d_out;

  char* ws = (char*)d_ws;
  short* L1b   = (short*)ws;                  // 384 KB
  short* L2cat = (short*)(ws + (384 << 10));  // 384 KB
  short* WT    = (short*)(ws + (768 << 10));  // 72 KB
  char* data = ws + (4ull << 20);

  // per-batch: HbT 8 MiB + A2 24 MiB = 32 MiB
  const size_t perb = 32ull << 20;
  size_t avail = (ws_size > (4ull << 20)) ? ws_size - (4ull << 20) : 0;
  int nb = 1;
  if (avail >= 8 * perb) nb = 8;
  else if (avail >= 4 * perb) nb = 4;
  else if (avail >= 2 * perb) nb = 2;

  short* HbT = (short*)data;
  short* A2  = (short*)(data + (size_t)nb * (8ull << 20));

  k_cvt_l1<<<768, 256, 0, stream>>>(L1, L1b);
  k_build_l2cat<<<dim3(8, 8, 3), dim3(32, 8), 0, stream>>>(L2, L2cat);
  k_build_wt<<<36, 256, 0, stream>>>(W, WT);

  for (int b0 = 0; b0 < 8; b0 += nb) {
    k_cvt_ht<<<dim3(512, 8, nb), dim3(32, 8), 0, stream>>>(H, HbT, b0);
    k_s1<<<dim3(128, 6, nb), 256, 0, stream>>>(L1b, HbT, A2);
    k_s23<<<nb * 256, 512, 0, stream>>>(A2, WT, L2cat, bias, out, b0);
  }
}

// Round 11
// 358.048 us; speedup vs baseline: 1.2266x; 1.2266x over previous
//
#include <hip/hip_runtime.h>

typedef __attribute__((ext_vector_type(8))) short s16x8;
typedef __attribute__((ext_vector_type(4))) float f32x4;

#define MFMA16 __builtin_amdgcn_mfma_f32_16x16x32_bf16
#define WAITVM(N) asm volatile("s_waitcnt vmcnt(" #N ")" ::: "memory")
#define SBAR() asm volatile("s_barrier" ::: "memory")
#define WAITLGKM0() asm volatile("s_waitcnt lgkmcnt(0)" ::: "memory")
#define SCHEDB() __builtin_amdgcn_sched_barrier(0)

__device__ __forceinline__ short f2bf(float x) {
  union { float f; unsigned u; } c; c.f = x;
  unsigned r = (c.u + 0x7fffu + ((c.u >> 16) & 1u)) >> 16;
  return (short)r;
}

__device__ __forceinline__ void gld16(const void* g, void* l) {
  __builtin_amdgcn_global_load_lds(
      (const __attribute__((address_space(1))) unsigned*)g,
      (__attribute__((address_space(3))) unsigned*)l, 16, 0, 0);
}

// BK=32 LDS tiles: involution slot ^= (row>>1)&3 on BOTH gld_lds source and
// ds_read (R3-verified, 0 bank conflicts):
//   stage: srow = lane>>2, selem = ((lane&3)^((lane>>3)&3))*8
//   read : koff = ((lane>>4)^((lane>>1)&3))*8
// Race discipline (R8-proven): wave-private strips restage the just-consumed
// buffer only AFTER the MFMAs, pinned by sched_barrier(0). Cross-wave LDS
// handoffs use lgkmcnt(0)+s_barrier on both sides.

// ---------------------------------------------------------------------------
// Prep
// ---------------------------------------------------------------------------
__global__ __launch_bounds__(256) void k_cvt_l1(const float* __restrict__ L1,
                                                short* __restrict__ L1b) {
  int i = blockIdx.x * 256 + threadIdx.x;
  L1b[i] = f2bf(L1[i]);
}

__global__ __launch_bounds__(256) void k_build_l2cat(const float* __restrict__ L2,
                                                     short* __restrict__ L2cat) {
  __shared__ float t[32][33];
  const int l = blockIdx.z, w0 = blockIdx.x * 32, z0 = blockIdx.y * 32;
  const int tx = threadIdx.x, ty = threadIdx.y;
  const float* src = L2 + (size_t)l * 65536;
  for (int i = ty; i < 32; i += 8) t[i][tx] = src[(size_t)(w0 + i) * 256 + z0 + tx];
  __syncthreads();
  for (int i = ty; i < 32; i += 8)
    L2cat[(size_t)(z0 + i) * 768 + l * 256 + w0 + tx] = f2bf(t[tx][i]);
}

__global__ __launch_bounds__(256) void k_build_wt(const float* __restrict__ W,
                                                  short* __restrict__ WT) {
  for (int idx = threadIdx.x + blockIdx.x * 256; idx < 192 * 192; idx += 256 * gridDim.x) {
    int lo = idx / 192, kf = idx % 192;
    int l = lo >> 6, o = lo & 63, k = kf / 64, f = kf & 63;
    WT[idx] = f2bf(W[(((size_t)(k * 3 + l) * 64 + f) << 6) + o]);
  }
}

__global__ __launch_bounds__(256) void k_cvt_ht(const float* __restrict__ H,
                                                short* __restrict__ HbT, int b0) {
  __shared__ float t[32][33];
  const int bc = blockIdx.z;
  const int wf0 = blockIdx.x * 32, v0 = blockIdx.y * 32;
  const int tx = threadIdx.x, ty = threadIdx.y;
  const float* src = H + ((size_t)(b0 + bc) * 256 + v0) * 16384;
  for (int i = ty; i < 32; i += 8) t[i][tx] = src[(size_t)i * 16384 + wf0 + tx];
  __syncthreads();
  short* dst = HbT + ((size_t)bc * 16384 + wf0) * 256;
  for (int i = ty; i < 32; i += 8) dst[(size_t)i * 256 + v0 + tx] = f2bf(t[tx][i]);
}

// ---------------------------------------------------------------------------
// S1: A2[((bc*256+u)*256+w)*192 + kk*64+f] = sum_v L1b[kk][u][v]*HbT[bc][w*64+f][v]
// 128x128 tile, BK=32, double-buffered (R5-proven). NEW epilogue: C-tile goes
// through LDS (XOR-swizzled slots) so each thread emits 8 contiguous 16B
// stores (one full 128B A2 row (u,w) per thread) instead of 64 scalar b16s.
// ---------------------------------------------------------------------------
__global__ __launch_bounds__(256, 4) void k_s1(const short* __restrict__ L1b,
                                               const short* __restrict__ HbT,
                                               short* __restrict__ A2) {
  __shared__ __align__(16) short SB[16384];  // 32 KB: K-loop tiles; epilogue C-tile
  short (*At)[4096] = (short(*)[4096])SB;
  short (*Bt)[4096] = (short(*)[4096])(SB + 8192);
  const int t = threadIdx.x, lane = t & 63, wid = t >> 6;
  const int n0 = blockIdx.x * 128;
  const int kk = blockIdx.y >> 1;
  const int u0 = (blockIdx.y & 1) * 128;
  const int bc = blockIdx.z;
  const short* Ag = L1b + (size_t)kk * 65536;
  const short* Bg = HbT + (size_t)bc * 16384 * 256;
  const int wm = wid >> 1, wn = wid & 1;
  const int srow = lane >> 2;
  const int selem = ((lane & 3) ^ ((lane >> 3) & 3)) * 8;
  const int koff = ((lane >> 4) ^ ((lane >> 1) & 3)) * 8;
  const int ar = lane & 15;
#pragma unroll
  for (int j = 0; j < 2; ++j) {
    const int rb = wid * 32 + j * 16;
    gld16(Ag + (size_t)(u0 + rb + srow) * 256 + selem, At[0] + rb * 32);
    gld16(Bg + (size_t)(n0 + rb + srow) * 256 + selem, Bt[0] + rb * 32);
  }
  __syncthreads();
  f32x4 acc[4][4] = {};
#pragma unroll
  for (int kt8 = 0; kt8 < 8; ++kt8) {
    const int cur = kt8 & 1;
    s16x8 a[4], b[4];
#pragma unroll
    for (int i = 0; i < 4; ++i)
      a[i] = *(const s16x8*)&At[cur][(wm * 64 + i * 16 + ar) * 32 + koff];
#pragma unroll
    for (int j = 0; j < 4; ++j)
      b[j] = *(const s16x8*)&Bt[cur][(wn * 64 + j * 16 + ar) * 32 + koff];
    if (kt8 < 7) {
#pragma unroll
      for (int j = 0; j < 2; ++j) {
        const int rb = wid * 32 + j * 16;
        gld16(Ag + (size_t)(u0 + rb + srow) * 256 + (kt8 + 1) * 32 + selem, At[cur ^ 1] + rb * 32);
        gld16(Bg + (size_t)(n0 + rb + srow) * 256 + (kt8 + 1) * 32 + selem, Bt[cur ^ 1] + rb * 32);
      }
    }
#pragma unroll
    for (int i = 0; i < 4; ++i)
#pragma unroll
      for (int j = 0; j < 4; ++j) acc[i][j] = MFMA16(a[i], b[j], acc[i][j], 0, 0, 0);
    __syncthreads();
  }
  // epilogue: scatter C to LDS (swizzled 16B slots: slot ^= row&7), then
  // linear 128B-per-thread A2 writes.
  const int cr = lane >> 4, cc = lane & 15;
#pragma unroll
  for (int i = 0; i < 4; ++i)
#pragma unroll
    for (int j = 0; j < 4; ++j) {
      const int col = wn * 64 + j * 16 + cc;
#pragma unroll
      for (int r = 0; r < 4; ++r) {
        const int row = wm * 64 + i * 16 + cr * 4 + r;
        SB[row * 128 + (((col >> 3) ^ (row & 7)) << 3) + (col & 7)] = f2bf(acc[i][j][r]);
      }
    }
  __syncthreads();
  const int u_l = t >> 1, h = t & 1;
  short* dst = A2 + (((size_t)bc * 256 + u0 + u_l) * 256 + blockIdx.x * 2 + h) * 192 + kk * 64;
#pragma unroll
  for (int q = 0; q < 8; ++q) {
    const int slot = (h * 8 + q) ^ (u_l & 7);
    *(float4*)(dst + q * 8) = *(const float4*)&SB[u_l * 128 + slot * 8];
  }
}

// ---------------------------------------------------------------------------
// S2+S3 fused (R9-proven structure + T5 setprio), one block per bu (512 thr).
// LDS 144 KB: P[64][768] 96K (Ws 72K overlaid) + depth-3 strips 8x3x2K = 48K.
// Phase 1: (192 lo) x (own 32 w), K=192: a=A2 strips, b=Ws, 24 MFMA/iter.
// Phase 2: (own 32 z) x (64 o), K=768: a=L2cat strips, b=P, 8 MFMA/iter.
// Counted vmcnt: steady VM(4), tail VM(2)/VM(0); depth-3 lookahead.
// ---------------------------------------------------------------------------
__global__ __launch_bounds__(512, 2) void k_s23(const short* __restrict__ A2,
                                                const short* __restrict__ WTg,
                                                const short* __restrict__ L2cat,
                                                const float* __restrict__ bias,
                                                float* __restrict__ out, int b0) {
  __shared__ __align__(16) short P[64 * 768];        // 96 KB; Ws overlays [0,72K)
  __shared__ __align__(16) short AtS[8][3][32 * 32]; // 48 KB strips
  short* Ws = P;
  const int t = threadIdx.x, lane = t & 63, wid = t >> 6;
  const int bul = blockIdx.x;
  const int ar = lane & 15, cc = ar, cr = lane >> 4, sl = lane & 7, ks = lane >> 4;
  const int srow = lane >> 2;
  const int selem = ((lane & 3) ^ ((lane >> 3) & 3)) * 8;
  const int koff = ((lane >> 4) ^ ((lane >> 1) & 3)) * 8;
  const short* A2g = A2 + (size_t)bul * 49152;

#define P1S(tt, bi)                                                                        \
  do {                                                                                     \
    gld16(A2g + (size_t)(wid * 32 + srow) * 192 + (tt) * 32 + selem, &AtS[wid][bi][0]);    \
    gld16(A2g + (size_t)(wid * 32 + 16 + srow) * 192 + (tt) * 32 + selem,                  \
          &AtS[wid][bi][512]);                                                             \
  } while (0)
#define P2S(tt, bi)                                                                        \
  do {                                                                                     \
    gld16(L2cat + (size_t)(wid * 32 + srow) * 768 + (tt) * 32 + selem, &AtS[wid][bi][0]);  \
    gld16(L2cat + (size_t)(wid * 32 + 16 + srow) * 768 + (tt) * 32 + selem,                \
          &AtS[wid][bi][512]);                                                             \
  } while (0)

  // prologue: A2 tiles 0-2 + full Ws (192 lo x 192 kf, 72 gld16 groups)
  P1S(0, 0);
  P1S(1, 1);
  P1S(2, 2);
  for (int s = wid; s < 72; s += 8) {
    const int t6 = s / 12, g = (s % 12) * 16;
    gld16(WTg + (size_t)(g + srow) * 192 + t6 * 32 + selem, Ws + ((size_t)t6 * 192 + g) * 32);
  }
  __syncthreads();  // full drain: tiles 0-2 + Ws resident; vmcnt = 0

  // ---- Phase 1: (192 lo) x (own 32 w), K=192, 6 iters ----
  f32x4 acc[12][2] = {};
#pragma unroll
  for (int kt6 = 0; kt6 < 6; ++kt6) {
    if (kt6 == 3) { WAITVM(4); } else if (kt6 == 4) { WAITVM(2); } else if (kt6 == 5) { WAITVM(0); }
    const short* stc = &AtS[wid][kt6 % 3][0];
    s16x8 a0 = *(const s16x8*)&stc[(0 + ar) * 32 + koff];
    s16x8 a1 = *(const s16x8*)&stc[(16 + ar) * 32 + koff];
    __builtin_amdgcn_s_setprio(1);
#pragma unroll
    for (int j2 = 0; j2 < 12; ++j2) {
      s16x8 b = *(const s16x8*)&Ws[((size_t)kt6 * 192 + j2 * 16 + ar) * 32 + koff];
      acc[j2][0] = MFMA16(a0, b, acc[j2][0], 0, 0, 0);
      acc[j2][1] = MFMA16(a1, b, acc[j2][1], 0, 0, 0);
    }
    __builtin_amdgcn_s_setprio(0);
    SCHEDB();  // pin restage after the MFMAs (this iter's strip reads consumed)
    if (kt6 == 0) { P1S(3, 0); } else if (kt6 == 1) { P1S(4, 1); } else if (kt6 == 2) { P1S(5, 2); }
  }
  WAITLGKM0();  // this wave's Ws/strip reads complete
  SBAR();       // all waves done reading Ws; region becomes P

  // phase-2 prefetch into strips (strips fully consumed in phase 1)
  P2S(0, 0);
  P2S(1, 1);
  P2S(2, 2);

  // acc -> P (packed b32, swizzled slots)
#pragma unroll
  for (int j2 = 0; j2 < 12; ++j2)
#pragma unroll
    for (int i = 0; i < 2; ++i)
#pragma unroll
      for (int rp = 0; rp < 2; ++rp) {
        const int r = rp * 2;
        const int w = wid * 32 + i * 16 + cr * 4 + r;
        const int lo = j2 * 16 + cc;
        const int l = lo >> 6, o = lo & 63;
        const int lw = l * 256 + w;
        const int addr = o * 768 + ((lw >> 3) ^ (o & 7)) * 8 + (lw & 7);
        unsigned lo16 = (unsigned short)f2bf(acc[j2][i][r]);
        unsigned hi16 = (unsigned short)f2bf(acc[j2][i][r + 1]);
        *(unsigned*)&P[addr] = lo16 | (hi16 << 16);
      }
  WAITLGKM0();  // P ds_writes drained (gld_lds is vmcnt, unaffected)
  SBAR();       // P visible to all waves

  // ---- Phase 2: (own 32 z) x (64 o), K=768, 24 iters ----
  f32x4 acc2[2][4] = {};
#pragma unroll
  for (int t2 = 0; t2 < 24; ++t2) {
    if (t2 < 22) { WAITVM(4); } else if (t2 == 22) { WAITVM(2); } else { WAITVM(0); }
    const short* stc = &AtS[wid][t2 % 3][0];
    s16x8 a0 = *(const s16x8*)&stc[(0 + ar) * 32 + koff];
    s16x8 a1 = *(const s16x8*)&stc[(16 + ar) * 32 + koff];
    const int S = t2 * 4 + ks;
    __builtin_amdgcn_s_setprio(1);
#pragma unroll
    for (int j = 0; j < 4; ++j) {
      s16x8 b = *(const s16x8*)&P[(j * 16 + ar) * 768 + (S ^ sl) * 8];
      acc2[0][j] = MFMA16(a0, b, acc2[0][j], 0, 0, 0);
      acc2[1][j] = MFMA16(a1, b, acc2[1][j], 0, 0, 0);
    }
    __builtin_amdgcn_s_setprio(0);
    SCHEDB();  // pin restage after the MFMAs
    if (t2 < 21) {
      if (t2 % 3 == 0) { P2S(t2 + 3, 0); } else if (t2 % 3 == 1) { P2S(t2 + 3, 1); } else { P2S(t2 + 3, 2); }
    }
  }
#undef P1S
#undef P2S

  // epilogue
  float* og = out + ((size_t)b0 * 256 + bul) * 16384;
#pragma unroll
  for (int i = 0; i < 2; ++i)
#pragma unroll
    for (int j = 0; j < 4; ++j) {
      const float bv = bias[j * 16 + cc];
#pragma unroll
      for (int r = 0; r < 4; ++r) {
        const int z = wid * 32 + i * 16 + cr * 4 + r;
        og[(size_t)z * 64 + j * 16 + cc] = fmaxf(acc2[i][j][r] + bv, 0.f);
      }
    }
}

// ---------------------------------------------------------------------------
extern "C" void kernel_launch(void* const* d_in, const int* in_sizes, int n_in,
                              void* d_out, int out_size, void* d_ws, size_t ws_size,
                              hipStream_t stream) {
  const float* H    = (const float*)d_in[0];
  const float* L1   = (const float*)d_in[1];
  const float* L2   = (const float*)d_in[2];
  const float* W    = (const float*)d_in[3];
  const float* bias = (const float*)d_in[4];
  float* out = (float*)d_out;

  char* ws = (char*)d_ws;
  short* L1b   = (short*)ws;                  // 384 KB
  short* L2cat = (short*)(ws + (384 << 10));  // 384 KB
  short* WT    = (short*)(ws + (768 << 10));  // 72 KB
  char* data = ws + (4ull << 20);

  // per-batch: HbT 8 MiB + A2 24 MiB = 32 MiB
  const size_t perb = 32ull << 20;
  size_t avail = (ws_size > (4ull << 20)) ? ws_size - (4ull << 20) : 0;
  int nb = 1;
  if (avail >= 8 * perb) nb = 8;
  else if (avail >= 4 * perb) nb = 4;
  else if (avail >= 2 * perb) nb = 2;

  short* HbT = (short*)data;
  short* A2  = (short*)(data + (size_t)nb * (8ull << 20));

  k_cvt_l1<<<768, 256, 0, stream>>>(L1, L1b);
  k_build_l2cat<<<dim3(8, 8, 3), dim3(32, 8), 0, stream>>>(L2, L2cat);
  k_build_wt<<<36, 256, 0, stream>>>(W, WT);

  for (int b0 = 0; b0 < 8; b0 += nb) {
    k_cvt_ht<<<dim3(512, 8, nb), dim3(32, 8), 0, stream>>>(H, HbT, b0);
    k_s1<<<dim3(128, 6, nb), 256, 0, stream>>>(L1b, HbT, A2);
    k_s23<<<nb * 256, 512, 0, stream>>>(A2, WT, L2cat, bias, out, b0);
  }
}

// Round 12
// 322.142 us; speedup vs baseline: 1.3634x; 1.1115x over previous
//
#include <hip/hip_runtime.h>

typedef __attribute__((ext_vector_type(8))) short s16x8;
typedef __attribute__((ext_vector_type(4))) float f32x4;

#define MFMA16 __builtin_amdgcn_mfma_f32_16x16x32_bf16
#define WAITVM(N) asm volatile("s_waitcnt vmcnt(" #N ")" ::: "memory")
#define SBAR() asm volatile("s_barrier" ::: "memory")
#define WAITLGKM0() asm volatile("s_waitcnt lgkmcnt(0)" ::: "memory")
#define SCHEDB() __builtin_amdgcn_sched_barrier(0)

__device__ __forceinline__ short f2bf(float x) {
  union { float f; unsigned u; } c; c.f = x;
  unsigned r = (c.u + 0x7fffu + ((c.u >> 16) & 1u)) >> 16;
  return (short)r;
}

__device__ __forceinline__ void gld16(const void* g, void* l) {
  __builtin_amdgcn_global_load_lds(
      (const __attribute__((address_space(1))) unsigned*)g,
      (__attribute__((address_space(3))) unsigned*)l, 16, 0, 0);
}

// BK=32 LDS tiles: involution slot ^= (row>>1)&3 on BOTH gld_lds source and
// ds_read (R3-verified, 0 bank conflicts):
//   stage: srow = lane>>2, selem = ((lane&3)^((lane>>3)&3))*8
//   read : koff = ((lane>>4)^((lane>>1)&3))*8
// Race discipline (R8-proven): wave-private strips restage the just-consumed
// buffer only AFTER the MFMAs, pinned by sched_barrier(0). Cross-wave LDS
// region reuse: lgkmcnt(0)+s_barrier on both sides.

// ---------------------------------------------------------------------------
// Prep
// ---------------------------------------------------------------------------
__global__ __launch_bounds__(256) void k_cvt_l1(const float* __restrict__ L1,
                                                short* __restrict__ L1b) {
  int i = blockIdx.x * 256 + threadIdx.x;
  L1b[i] = f2bf(L1[i]);
}

__global__ __launch_bounds__(256) void k_build_l2cat(const float* __restrict__ L2,
                                                     short* __restrict__ L2cat) {
  __shared__ float t[32][33];
  const int l = blockIdx.z, w0 = blockIdx.x * 32, z0 = blockIdx.y * 32;
  const int tx = threadIdx.x, ty = threadIdx.y;
  const float* src = L2 + (size_t)l * 65536;
  for (int i = ty; i < 32; i += 8) t[i][tx] = src[(size_t)(w0 + i) * 256 + z0 + tx];
  __syncthreads();
  for (int i = ty; i < 32; i += 8)
    L2cat[(size_t)(z0 + i) * 768 + l * 256 + w0 + tx] = f2bf(t[tx][i]);
}

__global__ __launch_bounds__(256) void k_build_wt(const float* __restrict__ W,
                                                  short* __restrict__ WT) {
  for (int idx = threadIdx.x + blockIdx.x * 256; idx < 192 * 192; idx += 256 * gridDim.x) {
    int lo = idx / 192, kf = idx % 192;
    int l = lo / 64, o = lo & 63, k = kf / 64, f = kf & 63;
    WT[idx] = f2bf(W[(((size_t)(k * 3 + l) * 64 + f) << 6) + o]);
  }
}

__global__ __launch_bounds__(256) void k_cvt_ht(const float* __restrict__ H,
                                                short* __restrict__ HbT, int b0) {
  __shared__ float t[32][33];
  const int bc = blockIdx.z;
  const int wf0 = blockIdx.x * 32, v0 = blockIdx.y * 32;
  const int tx = threadIdx.x, ty = threadIdx.y;
  const float* src = H + ((size_t)(b0 + bc) * 256 + v0) * 16384;
  for (int i = ty; i < 32; i += 8) t[i][tx] = src[(size_t)i * 16384 + wf0 + tx];
  __syncthreads();
  short* dst = HbT + ((size_t)bc * 16384 + wf0) * 256;
  for (int i = ty; i < 32; i += 8) dst[(size_t)i * 256 + v0 + tx] = f2bf(t[tx][i]);
}

// ---------------------------------------------------------------------------
// S1 (R5/R9 form — fastest measured): A2[((bc*256+u)*256+w)*192 + kk*64+f]
// 128x128 tile, BK=32, double-buffered, stage-before-MFMA, syncthreads.
// ---------------------------------------------------------------------------
__global__ __launch_bounds__(256, 4) void k_s1(const short* __restrict__ L1b,
                                               const short* __restrict__ HbT,
                                               short* __restrict__ A2) {
  __shared__ __align__(16) short At[2][128 * 32];
  __shared__ __align__(16) short Bt[2][128 * 32];
  const int t = threadIdx.x, lane = t & 63, wid = t >> 6;
  const int n0 = blockIdx.x * 128;
  const int kk = blockIdx.y >> 1;
  const int u0 = (blockIdx.y & 1) * 128;
  const int bc = blockIdx.z;
  const short* Ag = L1b + (size_t)kk * 65536;
  const short* Bg = HbT + (size_t)bc * 16384 * 256;
  const int wm = wid >> 1, wn = wid & 1;
  const int srow = lane >> 2;
  const int selem = ((lane & 3) ^ ((lane >> 3) & 3)) * 8;
  const int koff = ((lane >> 4) ^ ((lane >> 1) & 3)) * 8;
  const int ar = lane & 15;
#pragma unroll
  for (int j = 0; j < 2; ++j) {
    const int rb = wid * 32 + j * 16;
    gld16(Ag + (size_t)(u0 + rb + srow) * 256 + selem, At[0] + rb * 32);
    gld16(Bg + (size_t)(n0 + rb + srow) * 256 + selem, Bt[0] + rb * 32);
  }
  __syncthreads();
  f32x4 acc[4][4] = {};
#pragma unroll
  for (int kt8 = 0; kt8 < 8; ++kt8) {
    const int cur = kt8 & 1;
    s16x8 a[4], b[4];
#pragma unroll
    for (int i = 0; i < 4; ++i)
      a[i] = *(const s16x8*)&At[cur][(wm * 64 + i * 16 + ar) * 32 + koff];
#pragma unroll
    for (int j = 0; j < 4; ++j)
      b[j] = *(const s16x8*)&Bt[cur][(wn * 64 + j * 16 + ar) * 32 + koff];
    if (kt8 < 7) {
#pragma unroll
      for (int j = 0; j < 2; ++j) {
        const int rb = wid * 32 + j * 16;
        gld16(Ag + (size_t)(u0 + rb + srow) * 256 + (kt8 + 1) * 32 + selem, At[cur ^ 1] + rb * 32);
        gld16(Bg + (size_t)(n0 + rb + srow) * 256 + (kt8 + 1) * 32 + selem, Bt[cur ^ 1] + rb * 32);
      }
    }
#pragma unroll
    for (int i = 0; i < 4; ++i)
#pragma unroll
      for (int j = 0; j < 4; ++j) acc[i][j] = MFMA16(a[i], b[j], acc[i][j], 0, 0, 0);
    __syncthreads();
  }
  const int cr = lane >> 4, cc = lane & 15;
#pragma unroll
  for (int i = 0; i < 4; ++i)
#pragma unroll
    for (int j = 0; j < 4; ++j) {
      const int ncol = n0 + wn * 64 + j * 16 + cc;
      const int w = ncol >> 6, f = ncol & 63;
#pragma unroll
      for (int r = 0; r < 4; ++r) {
        const int u = u0 + wm * 64 + i * 16 + cr * 4 + r;
        A2[(((size_t)bc * 256 + u) * 256 + w) * 192 + kk * 64 + f] = f2bf(acc[i][j][r]);
      }
    }
}

// ---------------------------------------------------------------------------
// S2+S3 fused, one block per bu, L-SPLIT into 3 passes -> LDS 80 KB ->
// 2 blocks/CU (16 waves):
//   P_l[64 o][256 w] 32 KB (Ws_l 24 KB overlaid) + depth-3 strips 8x3x2K=48 KB.
// Per pass l: phase1_l: (64 o) x (own 32 w), K=192 (a=A2 strips, b=Ws_l,
//   8 MFMA/iter x 6); P_l handoff; phase2_l: (own 32 z) x (64 o), K=256
//   (a=L2cat strips cols [l*256,l*256+256), b=P_l, 8 MFMA/iter x 8),
//   acc2 accumulates across passes.
// vmcnt ladders (derived; 2 instr/tile, 3 tiles in flight):
//   phase1: VM(4),4,4,4,2,0   phase2: VM(4)x6,2,0
// ---------------------------------------------------------------------------
__global__ __launch_bounds__(512, 4) void k_s23(const short* __restrict__ A2,
                                                const short* __restrict__ WTg,
                                                const short* __restrict__ L2cat,
                                                const float* __restrict__ bias,
                                                float* __restrict__ out, int b0) {
  __shared__ __align__(16) short P[64 * 256];        // 32 KB; Ws_l overlays [0,24K)
  __shared__ __align__(16) short AtS[8][3][32 * 32]; // 48 KB strips
  short* Ws = P;
  const int t = threadIdx.x, lane = t & 63, wid = t >> 6;
  const int bul = blockIdx.x;
  const int ar = lane & 15, cc = ar, cr = lane >> 4, sl = lane & 7, ks = lane >> 4;
  const int srow = lane >> 2;
  const int selem = ((lane & 3) ^ ((lane >> 3) & 3)) * 8;
  const int koff = ((lane >> 4) ^ ((lane >> 1) & 3)) * 8;
  const short* A2g = A2 + (size_t)bul * 49152;

#define P1S(tt, bi)                                                                        \
  do {                                                                                     \
    gld16(A2g + (size_t)(wid * 32 + srow) * 192 + (tt) * 32 + selem, &AtS[wid][bi][0]);    \
    gld16(A2g + (size_t)(wid * 32 + 16 + srow) * 192 + (tt) * 32 + selem,                  \
          &AtS[wid][bi][512]);                                                             \
  } while (0)
#define P2S(tt, bi)                                                                        \
  do {                                                                                     \
    gld16(L2cat + (size_t)(wid * 32 + srow) * 768 + (tt) * 32 + selem, &AtS[wid][bi][0]);  \
    gld16(L2cat + (size_t)(wid * 32 + 16 + srow) * 768 + (tt) * 32 + selem,                \
          &AtS[wid][bi][512]);                                                             \
  } while (0)

  f32x4 acc2[2][4] = {};
#pragma unroll
  for (int l = 0; l < 3; ++l) {
    // ---- pass prologue: stage Ws_l (3 gld16/wave) then strips t0-2 (6) ----
    // Region safety: l==0 -> fresh; l>0 -> phase2_{l-1} ended with VM(0) and
    // its tail below did lgkm0+SBAR, so P region reads are complete.
    const short* WTl = WTg + (size_t)l * 64 * 192;
    for (int s = wid; s < 24; s += 8) {
      const int t6 = s / 4, g = (s & 3) * 16;
      gld16(WTl + (size_t)(g + srow) * 192 + t6 * 32 + selem, Ws + ((size_t)t6 * 64 + g) * 32);
    }
    P1S(0, 0);
    P1S(1, 1);
    P1S(2, 2);
    WAITVM(6);  // Ws_l landed (strips may be in flight)
    SBAR();     // Ws_l resident block-wide

    // ---- Phase 1_l: (64 o) x (own 32 w), K=192, 6 iters ----
    f32x4 acc[4][2] = {};
#pragma unroll
    for (int kt6 = 0; kt6 < 6; ++kt6) {
      if (kt6 < 4) { WAITVM(4); } else if (kt6 == 4) { WAITVM(2); } else { WAITVM(0); }
      const short* stc = &AtS[wid][kt6 % 3][0];
      s16x8 a0 = *(const s16x8*)&stc[(0 + ar) * 32 + koff];
      s16x8 a1 = *(const s16x8*)&stc[(16 + ar) * 32 + koff];
#pragma unroll
      for (int j2 = 0; j2 < 4; ++j2) {
        s16x8 b = *(const s16x8*)&Ws[((size_t)kt6 * 64 + j2 * 16 + ar) * 32 + koff];
        acc[j2][0] = MFMA16(a0, b, acc[j2][0], 0, 0, 0);
        acc[j2][1] = MFMA16(a1, b, acc[j2][1], 0, 0, 0);
      }
      SCHEDB();  // pin restage after MFMAs (this iter's strip consumed)
      if (kt6 == 0) { P1S(3, 0); } else if (kt6 == 1) { P1S(4, 1); } else if (kt6 == 2) { P1S(5, 2); }
    }
    WAITLGKM0();  // this wave's Ws_l/strip ds_reads complete
    SBAR();       // all waves done reading Ws_l; region becomes P_l

    // phase-2 strip prefetch (strips fully consumed; overlaps P writes)
    P2S(l * 8 + 0, 0);
    P2S(l * 8 + 1, 1);
    P2S(l * 8 + 2, 2);

    // acc -> P_l (packed b32, swizzled slots: slot = (w>>3) ^ (o&7))
#pragma unroll
    for (int j2 = 0; j2 < 4; ++j2)
#pragma unroll
      for (int i = 0; i < 2; ++i)
#pragma unroll
        for (int rp = 0; rp < 2; ++rp) {
          const int r = rp * 2;
          const int w = wid * 32 + i * 16 + cr * 4 + r;
          const int o = j2 * 16 + cc;
          const int addr = o * 256 + (((w >> 3) ^ (o & 7)) << 3) + (w & 7);
          unsigned lo16 = (unsigned short)f2bf(acc[j2][i][r]);
          unsigned hi16 = (unsigned short)f2bf(acc[j2][i][r + 1]);
          *(unsigned*)&P[addr] = lo16 | (hi16 << 16);
        }
    WAITLGKM0();  // P_l ds_writes drained (gld_lds is vmcnt, unaffected)
    SBAR();       // P_l visible block-wide

    // ---- Phase 2_l: (own 32 z) x (64 o), K=256, 8 iters, acc2 += ----
#pragma unroll
    for (int t2 = 0; t2 < 8; ++t2) {
      if (t2 < 6) { WAITVM(4); } else if (t2 == 6) { WAITVM(2); } else { WAITVM(0); }
      const short* stc = &AtS[wid][t2 % 3][0];
      s16x8 a0 = *(const s16x8*)&stc[(0 + ar) * 32 + koff];
      s16x8 a1 = *(const s16x8*)&stc[(16 + ar) * 32 + koff];
      const int S = t2 * 4 + ks;
#pragma unroll
      for (int j = 0; j < 4; ++j) {
        s16x8 b = *(const s16x8*)&P[(j * 16 + ar) * 256 + ((S ^ sl) << 3)];
        acc2[0][j] = MFMA16(a0, b, acc2[0][j], 0, 0, 0);
        acc2[1][j] = MFMA16(a1, b, acc2[1][j], 0, 0, 0);
      }
      SCHEDB();  // pin restage after MFMAs
      if (t2 < 5) {
        if (t2 % 3 == 0) { P2S(l * 8 + t2 + 3, 0); }
        else if (t2 % 3 == 1) { P2S(l * 8 + t2 + 3, 1); }
        else { P2S(l * 8 + t2 + 3, 2); }
      }
    }
    if (l < 2) {
      WAITLGKM0();  // this wave's P_l reads complete
      SBAR();       // all waves done with P_l; region can become Ws_{l+1}
    }
  }
#undef P1S
#undef P2S

  // epilogue
  float* og = out + ((size_t)b0 * 256 + bul) * 16384;
#pragma unroll
  for (int i = 0; i < 2; ++i)
#pragma unroll
    for (int j = 0; j < 4; ++j) {
      const float bv = bias[j * 16 + cc];
#pragma unroll
      for (int r = 0; r < 4; ++r) {
        const int z = wid * 32 + i * 16 + cr * 4 + r;
        og[(size_t)z * 64 + j * 16 + cc] = fmaxf(acc2[i][j][r] + bv, 0.f);
      }
    }
}

// ---------------------------------------------------------------------------
extern "C" void kernel_launch(void* const* d_in, const int* in_sizes, int n_in,
                              void* d_out, int out_size, void* d_ws, size_t ws_size,
                              hipStream_t stream) {
  const float* H    = (const float*)d_in[0];
  const float* L1   = (const float*)d_in[1];
  const float* L2   = (const float*)d_in[2];
  const float* W    = (const float*)d_in[3];
  const float* bias = (const float*)d_in[4];
  float* out = (float*)d_out;

  char* ws = (char*)d_ws;
  short* L1b   = (short*)ws;                  // 384 KB
  short* L2cat = (short*)(ws + (384 << 10));  // 384 KB
  short* WT    = (short*)(ws + (768 << 10));  // 72 KB
  char* data = ws + (4ull << 20);

  // per-batch: HbT 8 MiB + A2 24 MiB = 32 MiB
  const size_t perb = 32ull << 20;
  size_t avail = (ws_size > (4ull << 20)) ? ws_size - (4ull << 20) : 0;
  int nb = 1;
  if (avail >= 8 * perb) nb = 8;
  else if (avail >= 4 * perb) nb = 4;
  else if (avail >= 2 * perb) nb = 2;

  short* HbT = (short*)data;
  short* A2  = (short*)(data + (size_t)nb * (8ull << 20));

  k_cvt_l1<<<768, 256, 0, stream>>>(L1, L1b);
  k_build_l2cat<<<dim3(8, 8, 3), dim3(32, 8), 0, stream>>>(L2, L2cat);
  k_build_wt<<<36, 256, 0, stream>>>(W, WT);

  for (int b0 = 0; b0 < 8; b0 += nb) {
    k_cvt_ht<<<dim3(512, 8, nb), dim3(32, 8), 0, stream>>>(H, HbT, b0);
    k_s1<<<dim3(128, 6, nb), 256, 0, stream>>>(L1b, HbT, A2);
    k_s23<<<nb * 256, 512, 0, stream>>>(A2, WT, L2cat, bias, out, b0);
  }
}